// Round 7
// baseline (579.946 us; speedup 1.0000x reference)
//
#include <hip/hip_runtime.h>
#include <hip/hip_bf16.h>

#define N_NODES 50000
#define E_EDGES 800000

using u16 = unsigned short;
typedef short bf8 __attribute__((ext_vector_type(8)));
typedef float f32x4 __attribute__((ext_vector_type(4)));

__device__ __forceinline__ float bf2f(u16 h) {
    union { unsigned u; float f; } v;
    v.u = ((unsigned)h) << 16;
    return v.f;
}
__device__ __forceinline__ u16 f2bf(float f) {
    union { float f; unsigned u; } v;
    v.f = f;
    unsigned r = v.u + 0x7FFF + ((v.u >> 16) & 1);
    return (u16)(r >> 16);
}

// ---------------- weight pack: W[k][n] fp32 -> MFMA B-fragment order bf16 ----
// Wpack chunk c = (gni*KS + ks)*64 + lane holds 8 bf16:
//   B[n = gni*16 + (lane&15)][k = ks*32 + (lane>>4)*8 + j]
struct WtArgs {
    const float* src[9];
    u16* dst[9];
    int K[9];
    int N[9];
};

__global__ __launch_bounds__(256) void k_wpack(WtArgs a) {
    int wi = blockIdx.y;
    int K = a.K[wi], NC = a.N[wi];
    int KS = K / 32;
    int chunks = (NC / 16) * KS * 64;
    for (int c = blockIdx.x * 256 + threadIdx.x; c < chunks;
         c += gridDim.x * 256) {
        int l = c & 63;
        int rest = c >> 6;  // gni*KS + ks
        int ks = rest % KS, gni = rest / KS;
        int n = gni * 16 + (l & 15);
        int kb = ks * 32 + (l >> 4) * 8;
        u16 outv[8];
#pragma unroll
        for (int j = 0; j < 8; ++j)
            outv[j] = f2bf(a.src[wi][(size_t)(kb + j) * NC + n]);
        *(bf8*)&a.dst[wi][(size_t)c * 8] = *(bf8*)outv;
    }
}

// ---------------- prep: h0 = x/1000 - 0.5, fp32 -> bf16 ----------------
__global__ __launch_bounds__(256) void k_prep(const float* __restrict__ x,
                                              u16* __restrict__ h0) {
    int total = N_NODES * 128 / 4;
    for (int i = blockIdx.x * 256 + threadIdx.x; i < total;
         i += gridDim.x * 256) {
        float4 v = *(const float4*)(x + (size_t)i * 4);
        ushort4 o;
        o.x = f2bf(v.x * 0.001f - 0.5f);
        o.y = f2bf(v.y * 0.001f - 0.5f);
        o.z = f2bf(v.z * 0.001f - 0.5f);
        o.w = f2bf(v.w * 0.001f - 0.5f);
        *(ushort4*)(h0 + (size_t)i * 4) = o;
    }
}

// ---------------- degree count ----------------
__global__ void k_count(const int* __restrict__ dst, int* __restrict__ deg) {
    for (int i = blockIdx.x * blockDim.x + threadIdx.x; i < E_EDGES;
         i += gridDim.x * blockDim.x)
        atomicAdd(&deg[dst[i]], 1);
}

// ---------------- 3-phase parallel exclusive scan ----------------
#define SCAN_B 49  // ceil(50000/1024)

__global__ __launch_bounds__(1024) void k_scan1(const int* __restrict__ deg,
                                                int* __restrict__ bsum) {
    __shared__ int sm[1024];
    int i = blockIdx.x * 1024 + threadIdx.x;
    sm[threadIdx.x] = (i < N_NODES) ? deg[i] : 0;
    __syncthreads();
    for (int ofs = 512; ofs > 0; ofs >>= 1) {
        if (threadIdx.x < ofs) sm[threadIdx.x] += sm[threadIdx.x + ofs];
        __syncthreads();
    }
    if (threadIdx.x == 0) bsum[blockIdx.x] = sm[0];
}

__global__ void k_scan2(const int* __restrict__ bsum, int* __restrict__ bofs) {
    int l = threadIdx.x;  // one wave of 64
    int v = (l < SCAN_B) ? bsum[l] : 0;
    int orig = v;
    for (int d = 1; d < 64; d <<= 1) {
        int u = __shfl_up(v, d, 64);
        if (l >= d) v += u;
    }
    if (l < SCAN_B) bofs[l] = v - orig;  // exclusive
}

__global__ __launch_bounds__(1024) void k_scan3(const int* __restrict__ deg,
                                                const int* __restrict__ bofs,
                                                int* __restrict__ rowptr,
                                                float* __restrict__ dinv) {
    __shared__ int sm[1024];
    int i = blockIdx.x * 1024 + threadIdx.x;
    int d = (i < N_NODES) ? deg[i] : 0;
    sm[threadIdx.x] = d;
    __syncthreads();
    for (int ofs = 1; ofs < 1024; ofs <<= 1) {
        int u = (threadIdx.x >= (unsigned)ofs) ? sm[threadIdx.x - ofs] : 0;
        __syncthreads();
        sm[threadIdx.x] += u;
        __syncthreads();
    }
    if (i < N_NODES) {
        int incl = sm[threadIdx.x] + bofs[blockIdx.x];
        rowptr[i] = incl - d;
        dinv[i] = 1.0f / fmaxf((float)d, 1.0f);
        if (i == N_NODES - 1) rowptr[N_NODES] = incl;
    }
}

// ---------------- CSR fill ----------------
__global__ void k_fill(const int* __restrict__ src, const int* __restrict__ dst,
                       const int* __restrict__ rowptr, int* __restrict__ cursor,
                       int* __restrict__ colidx) {
    for (int i = blockIdx.x * blockDim.x + threadIdx.x; i < E_EDGES;
         i += gridDim.x * blockDim.x) {
        int d = dst[i];
        int pos = rowptr[d] + atomicAdd(&cursor[d], 1);
        colidx[pos] = src[i];
    }
}

// ---------------- fused SAGE conv: in-register gather-mean + MFMA GEMM ------
// 256 threads = 4 waves; wave owns a 16-row strip, all NC cols.
// Lane (lr,sub) gather-accumulates its MFMA A-fragment slice of mean(h) in
// f32 regs over the row's CSR neighbors, converts to bf16 frags, then:
//   acc = meanfrag @ Wp1 + selffrag(global stream) @ Wp2
// B-frags come from pre-packed L2-resident weights, 16B/lane coalesced.
// No LDS, no barriers. VAE epilogue fuses the reparameterization.
enum { ACT_NONE = 0, ACT_SIN = 1, ACT_RELU = 2, ACT_SIGMOID1000 = 3, ACT_VAE = 4 };

template <int K, int NC, int ACT, bool OUT_F32, bool GATHER>
__global__ __launch_bounds__(256) void k_conv(
    const u16* __restrict__ H, const u16* __restrict__ Wp1,
    const u16* __restrict__ Wp2, const int* __restrict__ rowptr,
    const int* __restrict__ colidx, const float* __restrict__ dinv,
    const float* __restrict__ bias, void* __restrict__ Cout,
    float* __restrict__ out_mean, float* __restrict__ out_lv,
    const float* __restrict__ eps) {
    constexpr int M = N_NODES;
    constexpr int KS = K / 32;   // 32-wide k-steps
    constexpr int NG = NC / 16;  // 16-wide col groups

    const int t = threadIdx.x;
    const int lane = t & 63;
    const int wave = t >> 6;
    const int lr = lane & 15;
    const int sub = lane >> 4;
    const int row0 = (blockIdx.x * 4 + wave) * 16;
    const int row = row0 + lr;
    const bool rowOK = row < M;

    f32x4 acc[NG];
#pragma unroll
    for (int i = 0; i < NG; ++i) acc[i] = (f32x4){0.f, 0.f, 0.f, 0.f};

    if (GATHER) {
        // ---- gather-mean into registers (exact MFMA A-frag layout) ----
        float ga[K / 4];
#pragma unroll
        for (int i = 0; i < K / 4; ++i) ga[i] = 0.f;
        int beg = 0, end = 0;
        if (rowOK) {
            beg = rowptr[row];
            end = rowptr[row + 1];
        }
        const u16* hs = H + sub * 8;
        for (int e = beg; e < end; ++e) {
            int s = colidx[e];
            const u16* hp = hs + (size_t)s * K;
#pragma unroll
            for (int tt = 0; tt < KS; ++tt) {
                bf8 v = *(const bf8*)(hp + tt * 32);
#pragma unroll
                for (int j = 0; j < 8; ++j) ga[tt * 8 + j] += bf2f((u16)v[j]);
            }
        }
        float inv = rowOK ? dinv[row] : 0.f;
        bf8 a1[KS];
#pragma unroll
        for (int tt = 0; tt < KS; ++tt) {
            u16 tmpv[8];
#pragma unroll
            for (int j = 0; j < 8; ++j) tmpv[j] = f2bf(ga[tt * 8 + j] * inv);
            a1[tt] = *(bf8*)tmpv;
        }
        // ---- pass 1: mean @ Wl (A in regs) ----
#pragma unroll
        for (int ks = 0; ks < KS; ++ks) {
#pragma unroll
            for (int ni = 0; ni < NG; ++ni) {
                bf8 b = *(const bf8*)(Wp1 +
                                      (((size_t)ni * KS + ks) * 64 + lane) * 8);
                acc[ni] =
                    __builtin_amdgcn_mfma_f32_16x16x32_bf16(a1[ks], b, acc[ni],
                                                            0, 0, 0);
            }
        }
    }

    // ---- pass 2 (or only pass): self @ Wr, A streamed from global ----
    {
        const u16* ap = H + (size_t)row * K + sub * 8;
#pragma unroll
        for (int ks = 0; ks < KS; ++ks) {
            bf8 a = {0, 0, 0, 0, 0, 0, 0, 0};
            if (rowOK) a = *(const bf8*)(ap + ks * 32);
#pragma unroll
            for (int ni = 0; ni < NG; ++ni) {
                bf8 b = *(const bf8*)(Wp2 +
                                      (((size_t)ni * KS + ks) * 64 + lane) * 8);
                acc[ni] =
                    __builtin_amdgcn_mfma_f32_16x16x32_bf16(a, b, acc[ni], 0, 0,
                                                            0);
            }
        }
    }

    // ---- epilogue ----
    if (ACT == ACT_VAE) {
        // NC == 256: ni<8 = mean cols, ni+8 = matching log_var cols.
#pragma unroll
        for (int ni = 0; ni < 8; ++ni) {
            int colm = ni * 16 + lr;  // 0..127
            float bm = bias[colm];
            float bl = bias[colm + 128];
#pragma unroll
            for (int r = 0; r < 4; ++r) {
                int orow = row0 + sub * 4 + r;
                if (orow >= M) continue;
                float mv = acc[ni][r] + bm;
                float lv = acc[ni + 8][r] + bl;
                size_t o = (size_t)orow * 128 + colm;
                out_mean[o] = mv;
                out_lv[o] = lv;
                ((u16*)Cout)[o] = f2bf(mv + __expf(lv) * eps[o]);
            }
        }
    } else {
#pragma unroll
        for (int ni = 0; ni < NG; ++ni) {
            int col = ni * 16 + lr;
            float bv = bias[col];
#pragma unroll
            for (int r = 0; r < 4; ++r) {
                int orow = row0 + sub * 4 + r;
                if (orow >= M) continue;
                float v = acc[ni][r] + bv;
                if (ACT == ACT_SIN) v = __sinf(v);
                else if (ACT == ACT_RELU) v = fmaxf(v, 0.f);
                else if (ACT == ACT_SIGMOID1000) v = 1000.f / (1.f + __expf(-v));
                if (OUT_F32)
                    ((float*)Cout)[(size_t)orow * NC + col] = v;
                else
                    ((u16*)Cout)[(size_t)orow * NC + col] = f2bf(v);
            }
        }
    }
}

extern "C" void kernel_launch(void* const* d_in, const int* in_sizes, int n_in,
                              void* d_out, int out_size, void* d_ws,
                              size_t ws_size, hipStream_t stream) {
    const int N = N_NODES;
    const float* x = (const float*)d_in[0];
    const int* ei = (const int*)d_in[1];
    const float* eps = (const float*)d_in[2];
    const float* Wl1 = (const float*)d_in[3];
    const float* bl1 = (const float*)d_in[4];
    const float* Wr1 = (const float*)d_in[5];
    const float* Wl2 = (const float*)d_in[6];
    const float* bl2 = (const float*)d_in[7];
    const float* Wr2 = (const float*)d_in[8];
    const float* Wl3 = (const float*)d_in[9];
    const float* bl3 = (const float*)d_in[10];
    const float* Wr3 = (const float*)d_in[11];
    const float* Wl4 = (const float*)d_in[12];
    const float* bl4 = (const float*)d_in[13];
    const float* Wr4 = (const float*)d_in[14];
    const float* W_lin = (const float*)d_in[15];
    const float* b_lin = (const float*)d_in[16];

    const int* src = ei;
    const int* dst = ei + E_EDGES;

    char* w = (char*)d_ws;
    auto alloc = [&](size_t b) {
        void* p = (void*)w;
        w += (b + 255) & ~(size_t)255;
        return p;
    };
    int* deg = (int*)alloc((size_t)N * 4);
    int* rowptr = (int*)alloc((size_t)(N + 1) * 4);
    int* cursor = (int*)alloc((size_t)N * 4);
    int* colidx = (int*)alloc((size_t)E_EDGES * 4);
    float* dinv = (float*)alloc((size_t)N * 4);
    int* bsum = (int*)alloc(64 * 4);
    int* bofs = (int*)alloc(64 * 4);
    u16* hb0 = (u16*)alloc((size_t)N * 256 * 2);
    u16* hb1 = (u16*)alloc((size_t)N * 256 * 2);
    u16* hb2 = (u16*)alloc((size_t)N * 256 * 2);
    static const int wK[9] = {128, 128, 256, 256, 128, 128, 128, 128, 128};
    static const int wN[9] = {256, 256, 256, 256, 128, 128, 128, 128, 64};
    u16* Wt[9];
    for (int i = 0; i < 9; ++i) Wt[i] = (u16*)alloc((size_t)wK[i] * wN[i] * 2);

    float* out_final = (float*)d_out;              // N x 64
    float* out_mean = out_final + (size_t)N * 64;  // N x 128
    float* out_lv = out_mean + (size_t)N * 128;    // N x 128

    hipMemsetAsync(deg, 0, (size_t)N * 4, stream);
    hipMemsetAsync(cursor, 0, (size_t)N * 4, stream);

    WtArgs wa;
    const float* wsrc[9] = {Wl1, Wr1, Wl2, Wr2, Wl3, Wr3, Wl4, Wr4, W_lin};
    for (int i = 0; i < 9; ++i) {
        wa.src[i] = wsrc[i];
        wa.dst[i] = Wt[i];
        wa.K[i] = wK[i];
        wa.N[i] = wN[i];
    }
    k_wpack<<<dim3(32, 9), 256, 0, stream>>>(wa);

    k_prep<<<2048, 256, 0, stream>>>(x, hb0);
    k_count<<<3125, 256, 0, stream>>>(dst, deg);
    k_scan1<<<SCAN_B, 1024, 0, stream>>>(deg, bsum);
    k_scan2<<<1, 64, 0, stream>>>(bsum, bofs);
    k_scan3<<<SCAN_B, 1024, 0, stream>>>(deg, bofs, rowptr, dinv);
    k_fill<<<3125, 256, 0, stream>>>(src, dst, rowptr, cursor, colidx);

    const int gx = (N / 16 + 3) / 4;  // 782 blocks, 4 wave-strips each

    // conv1: h1 = sin(mean(h0)@Wl1 + bl1 + h0@Wr1)   (N x 256) -> hb1
    k_conv<128, 256, ACT_SIN, false, true><<<gx, 256, 0, stream>>>(
        hb0, Wt[0], Wt[1], rowptr, colidx, dinv, bl1, hb1, nullptr, nullptr,
        nullptr);

    // conv2 + fused reparam: out_mean, out_lv, z(bf16) -> hb2 (N x 128)
    k_conv<256, 256, ACT_VAE, false, true><<<gx, 256, 0, stream>>>(
        hb1, Wt[2], Wt[3], rowptr, colidx, dinv, bl2, hb2, out_mean, out_lv,
        eps);

    // conv3: h3 = relu(mean(z)@Wl3 + bl3 + z@Wr3)    (N x 128) -> hb0
    k_conv<128, 128, ACT_RELU, false, true><<<gx, 256, 0, stream>>>(
        hb2, Wt[4], Wt[5], rowptr, colidx, dinv, bl3, hb0, nullptr, nullptr,
        nullptr);

    // conv4: h4 = relu(mean(h3)@Wl4 + bl4 + h3@Wr4)  (N x 128) -> hb1
    k_conv<128, 128, ACT_RELU, false, true><<<gx, 256, 0, stream>>>(
        hb0, Wt[6], Wt[7], rowptr, colidx, dinv, bl4, hb1, nullptr, nullptr,
        nullptr);

    // out = sigmoid(h4 @ W_lin + b_lin) * 1000       (N x 64, fp32) -> d_out
    k_conv<128, 64, ACT_SIGMOID1000, true, false><<<gx, 256, 0, stream>>>(
        hb1, Wt[8], Wt[8], nullptr, nullptr, nullptr, b_lin, out_final, nullptr,
        nullptr, nullptr);
}

// Round 8
// 411.804 us; speedup vs baseline: 1.4083x; 1.4083x over previous
//
#include <hip/hip_runtime.h>
#include <hip/hip_bf16.h>

#define N_NODES 50000
#define E_EDGES 800000

using u16 = unsigned short;
typedef short bf8 __attribute__((ext_vector_type(8)));
typedef float f32x4 __attribute__((ext_vector_type(4)));

__device__ __forceinline__ float bf2f(u16 h) {
    union { unsigned u; float f; } v;
    v.u = ((unsigned)h) << 16;
    return v.f;
}
__device__ __forceinline__ u16 f2bf(float f) {
    union { float f; unsigned u; } v;
    v.f = f;
    unsigned r = v.u + 0x7FFF + ((v.u >> 16) & 1);
    return (u16)(r >> 16);
}

// ---------------- weight transpose+cast: Wt[n][k] = bf16(W[k][n]) ----------------
struct WtArgs {
    const float* src[9];
    u16* dst[9];
    int K[9];
    int N[9];
};

__global__ __launch_bounds__(256) void k_wt(WtArgs a) {
    int wi = blockIdx.y;
    int K = a.K[wi], Nn = a.N[wi];
    int tot = K * Nn;
    for (int i = blockIdx.x * 256 + threadIdx.x; i < tot; i += gridDim.x * 256) {
        int n = i / K, k = i % K;
        a.dst[wi][i] = f2bf(a.src[wi][(size_t)k * Nn + n]);
    }
}

// ---------------- prep: h0 = x/1000 - 0.5, fp32 -> bf16 ----------------
__global__ __launch_bounds__(256) void k_prep(const float* __restrict__ x,
                                              u16* __restrict__ h0) {
    int total = N_NODES * 128 / 4;
    for (int i = blockIdx.x * 256 + threadIdx.x; i < total;
         i += gridDim.x * 256) {
        float4 v = *(const float4*)(x + (size_t)i * 4);
        ushort4 o;
        o.x = f2bf(v.x * 0.001f - 0.5f);
        o.y = f2bf(v.y * 0.001f - 0.5f);
        o.z = f2bf(v.z * 0.001f - 0.5f);
        o.w = f2bf(v.w * 0.001f - 0.5f);
        *(ushort4*)(h0 + (size_t)i * 4) = o;
    }
}

// ---------------- degree count ----------------
__global__ void k_count(const int* __restrict__ dst, int* __restrict__ deg) {
    for (int i = blockIdx.x * blockDim.x + threadIdx.x; i < E_EDGES;
         i += gridDim.x * blockDim.x)
        atomicAdd(&deg[dst[i]], 1);
}

// ---------------- 3-phase parallel exclusive scan ----------------
#define SCAN_B 49  // ceil(50000/1024)

__global__ __launch_bounds__(1024) void k_scan1(const int* __restrict__ deg,
                                                int* __restrict__ bsum) {
    __shared__ int sm[1024];
    int i = blockIdx.x * 1024 + threadIdx.x;
    sm[threadIdx.x] = (i < N_NODES) ? deg[i] : 0;
    __syncthreads();
    for (int ofs = 512; ofs > 0; ofs >>= 1) {
        if (threadIdx.x < ofs) sm[threadIdx.x] += sm[threadIdx.x + ofs];
        __syncthreads();
    }
    if (threadIdx.x == 0) bsum[blockIdx.x] = sm[0];
}

__global__ void k_scan2(const int* __restrict__ bsum, int* __restrict__ bofs) {
    int l = threadIdx.x;  // one wave of 64
    int v = (l < SCAN_B) ? bsum[l] : 0;
    int orig = v;
    for (int d = 1; d < 64; d <<= 1) {
        int u = __shfl_up(v, d, 64);
        if (l >= d) v += u;
    }
    if (l < SCAN_B) bofs[l] = v - orig;  // exclusive
}

__global__ __launch_bounds__(1024) void k_scan3(const int* __restrict__ deg,
                                                const int* __restrict__ bofs,
                                                int* __restrict__ rowptr,
                                                float* __restrict__ dinv) {
    __shared__ int sm[1024];
    int i = blockIdx.x * 1024 + threadIdx.x;
    int d = (i < N_NODES) ? deg[i] : 0;
    sm[threadIdx.x] = d;
    __syncthreads();
    for (int ofs = 1; ofs < 1024; ofs <<= 1) {
        int u = (threadIdx.x >= (unsigned)ofs) ? sm[threadIdx.x - ofs] : 0;
        __syncthreads();
        sm[threadIdx.x] += u;
        __syncthreads();
    }
    if (i < N_NODES) {
        int incl = sm[threadIdx.x] + bofs[blockIdx.x];
        rowptr[i] = incl - d;
        dinv[i] = 1.0f / fmaxf((float)d, 1.0f);
        if (i == N_NODES - 1) rowptr[N_NODES] = incl;
    }
}

// ---------------- CSR fill ----------------
__global__ void k_fill(const int* __restrict__ src, const int* __restrict__ dst,
                       const int* __restrict__ rowptr, int* __restrict__ cursor,
                       int* __restrict__ colidx) {
    for (int i = blockIdx.x * blockDim.x + threadIdx.x; i < E_EDGES;
         i += gridDim.x * blockDim.x) {
        int d = dst[i];
        int pos = rowptr[d] + atomicAdd(&cursor[d], 1);
        colidx[pos] = src[i];
    }
}

// ---------------- neighbor-mean aggregation: 1 wave/node, 16 lanes/edge ----------------
template <int D>
__global__ __launch_bounds__(256) void k_aggregate(
    const u16* __restrict__ h, const int* __restrict__ rowptr,
    const int* __restrict__ colidx, const float* __restrict__ dinv,
    u16* __restrict__ mean) {
    constexpr int VA = D / 16;  // bf16 per lane (8 or 16)
    int node = (int)((blockIdx.x * 256 + threadIdx.x) >> 6);
    int lane = threadIdx.x & 63;
    if (node >= N_NODES) return;
    int sub = lane >> 4, lr = lane & 15;
    int beg = rowptr[node], end = rowptr[node + 1];
    float acc[VA] = {};
    for (int e = beg + sub; e < end; e += 4) {
        int s = colidx[e];
        const u16* row = h + (size_t)s * D + lr * VA;
        bf8 r0 = *(const bf8*)row;
#pragma unroll
        for (int j = 0; j < 8; ++j) acc[j] += bf2f((u16)r0[j]);
        if (VA == 16) {
            bf8 r1 = *(const bf8*)(row + 8);
#pragma unroll
            for (int j = 0; j < 8; ++j) acc[8 + j] += bf2f((u16)r1[j]);
        }
    }
#pragma unroll
    for (int j = 0; j < VA; ++j) {
        acc[j] += __shfl_xor(acc[j], 16);
        acc[j] += __shfl_xor(acc[j], 32);
    }
    if (sub == 0) {
        float inv = dinv[node];
        u16 outv[VA];
#pragma unroll
        for (int j = 0; j < VA; ++j) outv[j] = f2bf(acc[j] * inv);
        u16* o = mean + (size_t)node * D + lr * VA;
        *(bf8*)o = *(bf8*)&outv[0];
        if (VA == 16) *(bf8*)(o + 8) = *(bf8*)&outv[8];
    }
}

// ---------------- bf16 MFMA GEMM, strip-per-wave, K-chunked W staging ----------------
// 512 threads = 8 waves; wave w owns rows [(bx*8+w)*16, +16); computes ALL NC cols.
// A-frags read directly from global (each A row read exactly once), prefetched
// into regs before the barrier. W staged in LDS in 64-wide K-chunks (<=37 KB).
// NO min-waves occupancy cap: the R5 cap (512,4) forced acc spills to scratch
// (VGPR 120->64, +49 MB traffic). Natural VGPR ~120 -> ~16 waves/CU, no spill.
enum { ACT_NONE = 0, ACT_SIN = 1, ACT_RELU = 2, ACT_SIGMOID1000 = 3, ACT_VAE = 4 };

template <int K, int NC, int ACT, bool OUT_F32, bool TWO_PASS>
__global__ __launch_bounds__(512) void k_gemm(
    const u16* __restrict__ A1, const u16* __restrict__ Wt1,
    const u16* __restrict__ A2, const u16* __restrict__ Wt2,
    const float* __restrict__ bias, void* __restrict__ Cout,
    float* __restrict__ out_mean, float* __restrict__ out_lv,
    const float* __restrict__ eps) {
    constexpr int BK = 64;       // K-chunk
    constexpr int PBK = BK + 8;  // padded LDS row stride (elements)
    constexpr int M = N_NODES;
    extern __shared__ char smem[];
    u16* Bs = (u16*)smem;  // [NC][PBK]

    const int t = threadIdx.x;
    const int lane = t & 63;
    const int wave = t >> 6;
    const int lr = lane & 15;
    const int sub = lane >> 4;
    const int row0 = (blockIdx.x * 8 + wave) * 16;
    const int arow = row0 + lr;
    const bool rowOK = arow < M;

    f32x4 acc[NC / 16];
#pragma unroll
    for (int i = 0; i < NC / 16; ++i) acc[i] = (f32x4){0.f, 0.f, 0.f, 0.f};

    // one pass over A@Wt, chunked by BK in K
    auto pass = [&](const u16* __restrict__ A, const u16* __restrict__ Wt) {
        const u16* ap = A + (size_t)arow * K + sub * 8;
#pragma unroll
        for (int c0 = 0; c0 < K; c0 += BK) {
            // stage W[:, c0:c0+64] -> LDS  (NC*8 bf8-chunks spread over 512 thr)
#pragma unroll
            for (int i = 0; i < NC * (BK / 8) / 512; ++i) {
                int c = t + i * 512;
                int r = c >> 3, kc = c & 7;
                *(bf8*)&Bs[r * PBK + kc * 8] =
                    *(const bf8*)(Wt + (size_t)r * K + c0 + kc * 8);
            }
            // prefetch this chunk's A fragments (overlaps the barrier)
            bf8 a0 = {0, 0, 0, 0, 0, 0, 0, 0}, a1 = a0;
            if (rowOK) {
                a0 = *(const bf8*)(ap + c0);
                a1 = *(const bf8*)(ap + c0 + 32);
            }
            __syncthreads();
#pragma unroll
            for (int ni = 0; ni < NC / 16; ++ni) {
                bf8 b = *(const bf8*)&Bs[(ni * 16 + lr) * PBK + sub * 8];
                acc[ni] =
                    __builtin_amdgcn_mfma_f32_16x16x32_bf16(a0, b, acc[ni], 0, 0, 0);
            }
#pragma unroll
            for (int ni = 0; ni < NC / 16; ++ni) {
                bf8 b = *(const bf8*)&Bs[(ni * 16 + lr) * PBK + 32 + sub * 8];
                acc[ni] =
                    __builtin_amdgcn_mfma_f32_16x16x32_bf16(a1, b, acc[ni], 0, 0, 0);
            }
            __syncthreads();
        }
    };

    pass(A1, Wt1);
    if (TWO_PASS) pass(A2, Wt2);

    if (ACT == ACT_VAE) {
        // NC == 256: cols 0-127 = mean, 128-255 = log_var; same lane holds both.
#pragma unroll
        for (int ni = 0; ni < 8; ++ni) {
            int col = ni * 16 + lr;
            float bm = bias[col];
            float bl = bias[col + 128];
#pragma unroll
            for (int r = 0; r < 4; ++r) {
                int row = row0 + sub * 4 + r;
                if (row >= M) continue;
                float mv = acc[ni][r] + bm;
                float lv = acc[ni + 8][r] + bl;
                size_t o = (size_t)row * 128 + col;
                out_mean[o] = mv;
                out_lv[o] = lv;
                ((u16*)Cout)[o] = f2bf(mv + __expf(lv) * eps[o]);
            }
        }
    } else {
#pragma unroll
        for (int ni = 0; ni < NC / 16; ++ni) {
            int col = ni * 16 + lr;
            float bv = bias[col];
#pragma unroll
            for (int r = 0; r < 4; ++r) {
                int row = row0 + sub * 4 + r;
                if (row >= M) continue;
                float v = acc[ni][r] + bv;
                if (ACT == ACT_SIN) v = __sinf(v);
                else if (ACT == ACT_RELU) v = fmaxf(v, 0.f);
                else if (ACT == ACT_SIGMOID1000) v = 1000.f / (1.f + __expf(-v));
                if (OUT_F32)
                    ((float*)Cout)[(size_t)row * NC + col] = v;
                else
                    ((u16*)Cout)[(size_t)row * NC + col] = f2bf(v);
            }
        }
    }
}

extern "C" void kernel_launch(void* const* d_in, const int* in_sizes, int n_in,
                              void* d_out, int out_size, void* d_ws,
                              size_t ws_size, hipStream_t stream) {
    const int N = N_NODES;
    const float* x = (const float*)d_in[0];
    const int* ei = (const int*)d_in[1];
    const float* eps = (const float*)d_in[2];
    const float* Wl1 = (const float*)d_in[3];
    const float* bl1 = (const float*)d_in[4];
    const float* Wr1 = (const float*)d_in[5];
    const float* Wl2 = (const float*)d_in[6];
    const float* bl2 = (const float*)d_in[7];
    const float* Wr2 = (const float*)d_in[8];
    const float* Wl3 = (const float*)d_in[9];
    const float* bl3 = (const float*)d_in[10];
    const float* Wr3 = (const float*)d_in[11];
    const float* Wl4 = (const float*)d_in[12];
    const float* bl4 = (const float*)d_in[13];
    const float* Wr4 = (const float*)d_in[14];
    const float* W_lin = (const float*)d_in[15];
    const float* b_lin = (const float*)d_in[16];

    const int* src = ei;
    const int* dst = ei + E_EDGES;

    char* w = (char*)d_ws;
    auto alloc = [&](size_t b) {
        void* p = (void*)w;
        w += (b + 255) & ~(size_t)255;
        return p;
    };
    int* deg = (int*)alloc((size_t)N * 4);
    int* rowptr = (int*)alloc((size_t)(N + 1) * 4);
    int* cursor = (int*)alloc((size_t)N * 4);
    int* colidx = (int*)alloc((size_t)E_EDGES * 4);
    float* dinv = (float*)alloc((size_t)N * 4);
    int* bsum = (int*)alloc(64 * 4);
    int* bofs = (int*)alloc(64 * 4);
    u16* hbA = (u16*)alloc((size_t)N * 256 * 2);
    u16* hbB = (u16*)alloc((size_t)N * 256 * 2);
    u16* hbC = (u16*)alloc((size_t)N * 256 * 2);
    static const int wK[9] = {128, 128, 256, 256, 128, 128, 128, 128, 128};
    static const int wN[9] = {256, 256, 256, 256, 128, 128, 128, 128, 64};
    u16* Wt[9];
    for (int i = 0; i < 9; ++i) Wt[i] = (u16*)alloc((size_t)wK[i] * wN[i] * 2);

    float* out_final = (float*)d_out;              // N x 64
    float* out_mean = out_final + (size_t)N * 64;  // N x 128
    float* out_lv = out_mean + (size_t)N * 128;    // N x 128

    hipMemsetAsync(deg, 0, (size_t)N * 4, stream);
    hipMemsetAsync(cursor, 0, (size_t)N * 4, stream);

    WtArgs wa;
    const float* wsrc[9] = {Wl1, Wr1, Wl2, Wr2, Wl3, Wr3, Wl4, Wr4, W_lin};
    for (int i = 0; i < 9; ++i) {
        wa.src[i] = wsrc[i];
        wa.dst[i] = Wt[i];
        wa.K[i] = wK[i];
        wa.N[i] = wN[i];
    }
    k_wt<<<dim3(64, 9), 256, 0, stream>>>(wa);

    k_prep<<<2048, 256, 0, stream>>>(x, hbA);
    k_count<<<3125, 256, 0, stream>>>(dst, deg);
    k_scan1<<<SCAN_B, 1024, 0, stream>>>(deg, bsum);
    k_scan2<<<1, 64, 0, stream>>>(bsum, bofs);
    k_scan3<<<SCAN_B, 1024, 0, stream>>>(deg, bofs, rowptr, dinv);
    k_fill<<<3125, 256, 0, stream>>>(src, dst, rowptr, cursor, colidx);

    const int aggBlocks = (N * 64 + 255) / 256;    // one wave per node
    const int gx = (N / 16 + 7) / 8;               // 391 blocks of 8 wave-strips
    auto shm = [](int NC) { return (size_t)NC * 72 * 2; };  // [NC][64+8] bf16

    // conv1: h1 = sin(mean(h0)@Wl1 + bl1 + h0@Wr1)  (N x 256) -> hbC
    k_aggregate<128><<<aggBlocks, 256, 0, stream>>>(hbA, rowptr, colidx, dinv,
                                                    hbB);
    k_gemm<128, 256, ACT_SIN, false, true><<<gx, 512, shm(256), stream>>>(
        hbB, Wt[0], hbA, Wt[1], bl1, hbC, nullptr, nullptr, nullptr);

    // conv2 + fused reparam: writes out_mean, out_lv, z(bf16)->hbA
    k_aggregate<256><<<aggBlocks, 256, 0, stream>>>(hbC, rowptr, colidx, dinv,
                                                    hbB);
    k_gemm<256, 256, ACT_VAE, false, true><<<gx, 512, shm(256), stream>>>(
        hbB, Wt[2], hbC, Wt[3], bl2, hbA, out_mean, out_lv, eps);

    // conv3: h3 = relu(mean(z)@Wl3 + bl3 + z@Wr3)   (N x 128) -> hbC
    k_aggregate<128><<<aggBlocks, 256, 0, stream>>>(hbA, rowptr, colidx, dinv,
                                                    hbB);
    k_gemm<128, 128, ACT_RELU, false, true><<<gx, 512, shm(128), stream>>>(
        hbB, Wt[4], hbA, Wt[5], bl3, hbC, nullptr, nullptr, nullptr);

    // conv4: h4 = relu(mean(h3)@Wl4 + bl4 + h3@Wr4) (N x 128) -> hbA
    k_aggregate<128><<<aggBlocks, 256, 0, stream>>>(hbC, rowptr, colidx, dinv,
                                                    hbB);
    k_gemm<128, 128, ACT_RELU, false, true><<<gx, 512, shm(128), stream>>>(
        hbB, Wt[6], hbC, Wt[7], bl4, hbA, nullptr, nullptr, nullptr);

    // out = sigmoid(h4 @ W_lin + b_lin) * 1000      (N x 64, fp32) -> d_out
    k_gemm<128, 64, ACT_SIGMOID1000, true, false>
        <<<gx, 512, shm(64), stream>>>(hbA, Wt[8], nullptr, nullptr, b_lin,
                                       out_final, nullptr, nullptr, nullptr);
}

// Round 10
// 380.602 us; speedup vs baseline: 1.5238x; 1.0820x over previous
//
#include <hip/hip_runtime.h>
#include <hip/hip_bf16.h>

#define N_NODES 50000
#define E_EDGES 800000

using u16 = unsigned short;
typedef short bf8 __attribute__((ext_vector_type(8)));
typedef float f32x4 __attribute__((ext_vector_type(4)));

__device__ __forceinline__ float bf2f(u16 h) {
    union { unsigned u; float f; } v;
    v.u = ((unsigned)h) << 16;
    return v.f;
}
__device__ __forceinline__ u16 f2bf(float f) {
    union { float f; unsigned u; } v;
    v.f = f;
    unsigned r = v.u + 0x7FFF + ((v.u >> 16) & 1);
    return (u16)(r >> 16);
}

// ---------------- weight transpose+cast: Wt[n][k] = bf16(W[k][n]) ----------------
struct WtArgs {
    const float* src[9];
    u16* dst[9];
    int K[9];
    int N[9];
};

__global__ __launch_bounds__(256) void k_wt(WtArgs a) {
    int wi = blockIdx.y;
    int K = a.K[wi], Nn = a.N[wi];
    int tot = K * Nn;
    for (int i = blockIdx.x * 256 + threadIdx.x; i < tot; i += gridDim.x * 256) {
        int n = i / K, k = i % K;
        a.dst[wi][i] = f2bf(a.src[wi][(size_t)k * Nn + n]);
    }
}

// ---------------- prep: h0 = x/1000 - 0.5, fp32 -> bf16 ----------------
__global__ __launch_bounds__(256) void k_prep(const float* __restrict__ x,
                                              u16* __restrict__ h0) {
    int total = N_NODES * 128 / 4;
    for (int i = blockIdx.x * 256 + threadIdx.x; i < total;
         i += gridDim.x * 256) {
        float4 v = *(const float4*)(x + (size_t)i * 4);
        ushort4 o;
        o.x = f2bf(v.x * 0.001f - 0.5f);
        o.y = f2bf(v.y * 0.001f - 0.5f);
        o.z = f2bf(v.z * 0.001f - 0.5f);
        o.w = f2bf(v.w * 0.001f - 0.5f);
        *(ushort4*)(h0 + (size_t)i * 4) = o;
    }
}

// ---------------- degree count ----------------
__global__ void k_count(const int* __restrict__ dst, int* __restrict__ deg) {
    for (int i = blockIdx.x * blockDim.x + threadIdx.x; i < E_EDGES;
         i += gridDim.x * blockDim.x)
        atomicAdd(&deg[dst[i]], 1);
}

// ---------------- 3-phase parallel exclusive scan ----------------
#define SCAN_B 49  // ceil(50000/1024)

__global__ __launch_bounds__(1024) void k_scan1(const int* __restrict__ deg,
                                                int* __restrict__ bsum) {
    __shared__ int sm[1024];
    int i = blockIdx.x * 1024 + threadIdx.x;
    sm[threadIdx.x] = (i < N_NODES) ? deg[i] : 0;
    __syncthreads();
    for (int ofs = 512; ofs > 0; ofs >>= 1) {
        if (threadIdx.x < ofs) sm[threadIdx.x] += sm[threadIdx.x + ofs];
        __syncthreads();
    }
    if (threadIdx.x == 0) bsum[blockIdx.x] = sm[0];
}

__global__ void k_scan2(const int* __restrict__ bsum, int* __restrict__ bofs) {
    int l = threadIdx.x;  // one wave of 64
    int v = (l < SCAN_B) ? bsum[l] : 0;
    int orig = v;
    for (int d = 1; d < 64; d <<= 1) {
        int u = __shfl_up(v, d, 64);
        if (l >= d) v += u;
    }
    if (l < SCAN_B) bofs[l] = v - orig;  // exclusive
}

__global__ __launch_bounds__(1024) void k_scan3(const int* __restrict__ deg,
                                                const int* __restrict__ bofs,
                                                int* __restrict__ rowptr,
                                                float* __restrict__ dinv) {
    __shared__ int sm[1024];
    int i = blockIdx.x * 1024 + threadIdx.x;
    int d = (i < N_NODES) ? deg[i] : 0;
    sm[threadIdx.x] = d;
    __syncthreads();
    for (int ofs = 1; ofs < 1024; ofs <<= 1) {
        int u = (threadIdx.x >= (unsigned)ofs) ? sm[threadIdx.x - ofs] : 0;
        __syncthreads();
        sm[threadIdx.x] += u;
        __syncthreads();
    }
    if (i < N_NODES) {
        int incl = sm[threadIdx.x] + bofs[blockIdx.x];
        rowptr[i] = incl - d;
        dinv[i] = 1.0f / fmaxf((float)d, 1.0f);
        if (i == N_NODES - 1) rowptr[N_NODES] = incl;
    }
}

// ---------------- CSR fill ----------------
__global__ void k_fill(const int* __restrict__ src, const int* __restrict__ dst,
                       const int* __restrict__ rowptr, int* __restrict__ cursor,
                       int* __restrict__ colidx) {
    for (int i = blockIdx.x * blockDim.x + threadIdx.x; i < E_EDGES;
         i += gridDim.x * blockDim.x) {
        int d = dst[i];
        int pos = rowptr[d] + atomicAdd(&cursor[d], 1);
        colidx[pos] = src[i];
    }
}

// ---------------- neighbor-mean aggregation: 1 wave/node, 16 lanes/edge ----------------
template <int D>
__global__ __launch_bounds__(256) void k_aggregate(
    const u16* __restrict__ h, const int* __restrict__ rowptr,
    const int* __restrict__ colidx, const float* __restrict__ dinv,
    u16* __restrict__ mean) {
    constexpr int VA = D / 16;  // bf16 per lane (8 or 16)
    int node = (int)((blockIdx.x * 256 + threadIdx.x) >> 6);
    int lane = threadIdx.x & 63;
    if (node >= N_NODES) return;
    int sub = lane >> 4, lr = lane & 15;
    int beg = rowptr[node], end = rowptr[node + 1];
    float acc[VA] = {};
    for (int e = beg + sub; e < end; e += 4) {
        int s = colidx[e];
        const u16* row = h + (size_t)s * D + lr * VA;
        bf8 r0 = *(const bf8*)row;
#pragma unroll
        for (int j = 0; j < 8; ++j) acc[j] += bf2f((u16)r0[j]);
        if (VA == 16) {
            bf8 r1 = *(const bf8*)(row + 8);
#pragma unroll
            for (int j = 0; j < 8; ++j) acc[8 + j] += bf2f((u16)r1[j]);
        }
    }
#pragma unroll
    for (int j = 0; j < VA; ++j) {
        acc[j] += __shfl_xor(acc[j], 16);
        acc[j] += __shfl_xor(acc[j], 32);
    }
    if (sub == 0) {
        float inv = dinv[node];
        u16 outv[VA];
#pragma unroll
        for (int j = 0; j < VA; ++j) outv[j] = f2bf(acc[j] * inv);
        u16* o = mean + (size_t)node * D + lr * VA;
        *(bf8*)o = *(bf8*)&outv[0];
        if (VA == 16) *(bf8*)(o + 8) = *(bf8*)&outv[8];
    }
}

// ---------------- bf16 MFMA GEMM: strip-per-wave, full-W LDS, N-split -------
// R4 structure (fastest measured): stage the whole W-tile once per pass
// (2 barriers/pass), then an uninterrupted K-loop: A streamed from global
// (each row read once per y-block), B from LDS. gridDim.y splits columns
// (NCB = NC/2) so the LDS tile fits 2-4 blocks/CU and the grid is 782 blocks.
// VAE pairs (mean col c, log_var col c+128) within one block.
enum { ACT_NONE = 0, ACT_SIN = 1, ACT_RELU = 2, ACT_SIGMOID1000 = 3, ACT_VAE = 4 };

template <int K, int NCB, int NC, int ACT, bool OUT_F32, bool TWO_PASS>
__global__ __launch_bounds__(512) void k_gemm(
    const u16* __restrict__ A1, const u16* __restrict__ Wt1,
    const u16* __restrict__ A2, const u16* __restrict__ Wt2,
    const float* __restrict__ bias, void* __restrict__ Cout,
    float* __restrict__ out_mean, float* __restrict__ out_lv,
    const float* __restrict__ eps) {
    constexpr int PK = K + 8;    // padded LDS row stride (elements)
    constexpr int M = N_NODES;
    constexpr int CH = K / 8;    // 16B chunks per W row
    constexpr int NG = NCB / 16; // col groups per block
    extern __shared__ char smem[];
    u16* Bs = (u16*)smem;  // [NCB][PK]

    const int t = threadIdx.x;
    const int lane = t & 63;
    const int wave = t >> 6;
    const int lr = lane & 15;
    const int sub = lane >> 4;
    const int y = blockIdx.y;
    const int row0 = (blockIdx.x * 8 + wave) * 16;
    const int arow = row0 + lr;
    const bool rowOK = arow < M;

    // local W row -> global Wt row
    auto mapRow = [&](int r) {
        if (ACT == ACT_VAE)
            return r < NCB / 2 ? y * (NCB / 2) + r
                               : NC / 2 + y * (NCB / 2) + (r - NCB / 2);
        return y * NCB + r;
    };

    f32x4 acc[NG];
#pragma unroll
    for (int i = 0; i < NG; ++i) acc[i] = (f32x4){0.f, 0.f, 0.f, 0.f};

    auto pass = [&](const u16* __restrict__ A, const u16* __restrict__ Wt) {
        // stage W-tile (NCB x K) into LDS
#pragma unroll
        for (int i = 0; i < NCB * CH / 512; ++i) {
            int c = t + i * 512;
            int r = c / CH, kc = c % CH;
            *(bf8*)&Bs[r * PK + kc * 8] =
                *(const bf8*)(Wt + (size_t)mapRow(r) * K + kc * 8);
        }
        // prefetch first A fragment (overlaps the barrier)
        const u16* ap = A + (size_t)arow * K + sub * 8;
        bf8 a0 = {0, 0, 0, 0, 0, 0, 0, 0};
        if (rowOK) a0 = *(const bf8*)ap;
        __syncthreads();
#pragma unroll
        for (int ks = 0; ks < K / 32; ++ks) {
            bf8 a = a0;
            if (ks > 0) {
                a = (bf8){0, 0, 0, 0, 0, 0, 0, 0};
                if (rowOK) a = *(const bf8*)(ap + ks * 32);
            }
#pragma unroll
            for (int ni = 0; ni < NG; ++ni) {
                bf8 b = *(const bf8*)&Bs[(ni * 16 + lr) * PK + ks * 32 + sub * 8];
                acc[ni] =
                    __builtin_amdgcn_mfma_f32_16x16x32_bf16(a, b, acc[ni], 0, 0, 0);
            }
        }
        __syncthreads();
    };

    pass(A1, Wt1);
    if (TWO_PASS) pass(A2, Wt2);

    if (ACT == ACT_VAE) {
        // NG local groups: ni < NG/2 = mean cols (global y*64+...),
        // ni+NG/2 = matching log_var cols (+128).
#pragma unroll
        for (int ni = 0; ni < NG / 2; ++ni) {
            int colm = y * (NCB / 2) + ni * 16 + lr;  // y*64 + ni*16 + lr
            float bm = bias[colm];
            float bl = bias[colm + 128];
#pragma unroll
            for (int r = 0; r < 4; ++r) {
                int row = row0 + sub * 4 + r;
                if (row >= M) continue;
                float mv = acc[ni][r] + bm;
                float lv = acc[ni + NG / 2][r] + bl;
                size_t o = (size_t)row * 128 + colm;
                out_mean[o] = mv;
                out_lv[o] = lv;
                ((u16*)Cout)[o] = f2bf(mv + __expf(lv) * eps[o]);
            }
        }
    } else {
#pragma unroll
        for (int ni = 0; ni < NG; ++ni) {
            int col = y * NCB + ni * 16 + lr;
            float bv = bias[col];
#pragma unroll
            for (int r = 0; r < 4; ++r) {
                int row = row0 + sub * 4 + r;
                if (row >= M) continue;
                float v = acc[ni][r] + bv;
                if (ACT == ACT_SIN) v = __sinf(v);
                else if (ACT == ACT_RELU) v = fmaxf(v, 0.f);
                else if (ACT == ACT_SIGMOID1000) v = 1000.f / (1.f + __expf(-v));
                if (OUT_F32)
                    ((float*)Cout)[(size_t)row * NC + col] = v;
                else
                    ((u16*)Cout)[(size_t)row * NC + col] = f2bf(v);
            }
        }
    }
}

extern "C" void kernel_launch(void* const* d_in, const int* in_sizes, int n_in,
                              void* d_out, int out_size, void* d_ws,
                              size_t ws_size, hipStream_t stream) {
    const int N = N_NODES;
    const float* x = (const float*)d_in[0];
    const int* ei = (const int*)d_in[1];
    const float* eps = (const float*)d_in[2];
    const float* Wl1 = (const float*)d_in[3];
    const float* bl1 = (const float*)d_in[4];
    const float* Wr1 = (const float*)d_in[5];
    const float* Wl2 = (const float*)d_in[6];
    const float* bl2 = (const float*)d_in[7];
    const float* Wr2 = (const float*)d_in[8];
    const float* Wl3 = (const float*)d_in[9];
    const float* bl3 = (const float*)d_in[10];
    const float* Wr3 = (const float*)d_in[11];
    const float* Wl4 = (const float*)d_in[12];
    const float* bl4 = (const float*)d_in[13];
    const float* Wr4 = (const float*)d_in[14];
    const float* W_lin = (const float*)d_in[15];
    const float* b_lin = (const float*)d_in[16];

    const int* src = ei;
    const int* dst = ei + E_EDGES;

    char* w = (char*)d_ws;
    auto alloc = [&](size_t b) {
        void* p = (void*)w;
        w += (b + 255) & ~(size_t)255;
        return p;
    };
    int* deg = (int*)alloc((size_t)N * 4);
    int* rowptr = (int*)alloc((size_t)(N + 1) * 4);
    int* cursor = (int*)alloc((size_t)N * 4);
    int* colidx = (int*)alloc((size_t)E_EDGES * 4);
    float* dinv = (float*)alloc((size_t)N * 4);
    int* bsum = (int*)alloc(64 * 4);
    int* bofs = (int*)alloc(64 * 4);
    u16* hbA = (u16*)alloc((size_t)N * 256 * 2);
    u16* hbB = (u16*)alloc((size_t)N * 256 * 2);
    u16* hbC = (u16*)alloc((size_t)N * 256 * 2);
    static const int wK[9] = {128, 128, 256, 256, 128, 128, 128, 128, 128};
    static const int wN[9] = {256, 256, 256, 256, 128, 128, 128, 128, 64};
    u16* Wt[9];
    for (int i = 0; i < 9; ++i) Wt[i] = (u16*)alloc((size_t)wK[i] * wN[i] * 2);

    float* out_final = (float*)d_out;              // N x 64
    float* out_mean = out_final + (size_t)N * 64;  // N x 128
    float* out_lv = out_mean + (size_t)N * 128;    // N x 128

    hipMemsetAsync(deg, 0, (size_t)N * 4, stream);
    hipMemsetAsync(cursor, 0, (size_t)N * 4, stream);

    WtArgs wa;
    const float* wsrc[9] = {Wl1, Wr1, Wl2, Wr2, Wl3, Wr3, Wl4, Wr4, W_lin};
    for (int i = 0; i < 9; ++i) {
        wa.src[i] = wsrc[i];
        wa.dst[i] = Wt[i];
        wa.K[i] = wK[i];
        wa.N[i] = wN[i];
    }
    k_wt<<<dim3(64, 9), 256, 0, stream>>>(wa);

    k_prep<<<2048, 256, 0, stream>>>(x, hbA);
    k_count<<<3125, 256, 0, stream>>>(dst, deg);
    k_scan1<<<SCAN_B, 1024, 0, stream>>>(deg, bsum);
    k_scan2<<<1, 64, 0, stream>>>(bsum, bofs);
    k_scan3<<<SCAN_B, 1024, 0, stream>>>(deg, bofs, rowptr, dinv);
    k_fill<<<3125, 256, 0, stream>>>(src, dst, rowptr, cursor, colidx);

    const int aggBlocks = (N * 64 + 255) / 256;  // one wave per node
    const int gx = (N / 16 + 7) / 8;             // 391 x-blocks of 8 wave-strips
    auto shm = [](int NCB, int K) { return (size_t)NCB * (K + 8) * 2; };

    // conv1: h1 = sin(mean(h0)@Wl1 + bl1 + h0@Wr1)  (N x 256) -> hbC
    k_aggregate<128><<<aggBlocks, 256, 0, stream>>>(hbA, rowptr, colidx, dinv,
                                                    hbB);
    k_gemm<128, 128, 256, ACT_SIN, false, true>
        <<<dim3(gx, 2), 512, shm(128, 128), stream>>>(hbB, Wt[0], hbA, Wt[1],
                                                      bl1, hbC, nullptr,
                                                      nullptr, nullptr);

    // conv2 + fused reparam: writes out_mean, out_lv, z(bf16)->hbA
    k_aggregate<256><<<aggBlocks, 256, 0, stream>>>(hbC, rowptr, colidx, dinv,
                                                    hbB);
    k_gemm<256, 128, 256, ACT_VAE, false, true>
        <<<dim3(gx, 2), 512, shm(128, 256), stream>>>(hbB, Wt[2], hbC, Wt[3],
                                                      bl2, hbA, out_mean,
                                                      out_lv, eps);

    // conv3: h3 = relu(mean(z)@Wl3 + bl3 + z@Wr3)   (N x 128) -> hbC
    k_aggregate<128><<<aggBlocks, 256, 0, stream>>>(hbA, rowptr, colidx, dinv,
                                                    hbB);
    k_gemm<128, 64, 128, ACT_RELU, false, true>
        <<<dim3(gx, 2), 512, shm(64, 128), stream>>>(hbB, Wt[4], hbA, Wt[5],
                                                     bl3, hbC, nullptr, nullptr,
                                                     nullptr);

    // conv4: h4 = relu(mean(h3)@Wl4 + bl4 + h3@Wr4) (N x 128) -> hbA
    k_aggregate<128><<<aggBlocks, 256, 0, stream>>>(hbC, rowptr, colidx, dinv,
                                                    hbB);
    k_gemm<128, 64, 128, ACT_RELU, false, true>
        <<<dim3(gx, 2), 512, shm(64, 128), stream>>>(hbB, Wt[6], hbC, Wt[7],
                                                     bl4, hbA, nullptr, nullptr,
                                                     nullptr);

    // out = sigmoid(h4 @ W_lin + b_lin) * 1000      (N x 64, fp32) -> d_out
    k_gemm<128, 32, 64, ACT_SIGMOID1000, true, false>
        <<<dim3(gx, 2), 512, shm(32, 128), stream>>>(hbA, Wt[8], nullptr,
                                                     nullptr, b_lin, out_final,
                                                     nullptr, nullptr, nullptr);
}